// Round 2
// baseline (1256.618 us; speedup 1.0000x reference)
//
#include <hip/hip_runtime.h>
#include <hip/hip_bf16.h>
#include <cstdint>
#include <cstddef>

#define N_NODES 50000
#define N_EDGES 1600000
#define N_FEAT  512
#define N_HID   256
#define N_CLS   64
#define K_HOPS  10

typedef __attribute__((ext_vector_type(4))) float f32x4;
typedef __attribute__((ext_vector_type(8))) short s16x8;

__device__ __forceinline__ ushort f2bf(float f) {
    uint32_t u = __float_as_uint(f);
    uint32_t r = (u + 0x7FFFu + ((u >> 16) & 1u)) >> 16;
    return (ushort)r;
}

// ---------------- GEMM1: H = relu(X @ W1^T), bf16 MFMA, 128x128 tile, BK=64 ----
__launch_bounds__(256)
__global__ void gemm1_k(const float* __restrict__ X, const float* __restrict__ W1,
                        ushort* __restrict__ H) {
    __shared__ ushort sA[128 * 64];
    __shared__ ushort sB[128 * 64];
    const int m0 = blockIdx.x * 128;
    const int n0 = blockIdx.y * 128;
    const int t = threadIdx.x;
    const int wid = t >> 6, lane = t & 63;
    const int wr = wid >> 1, wc = wid & 1;
    const int lo = lane & 15, hi = lane >> 4;

    f32x4 acc[4][4] = {};

    for (int kt = 0; kt < N_FEAT; kt += 64) {
        // stage A (fp32 -> bf16), 128 rows x 64 k
        #pragma unroll
        for (int p = 0; p < 8; ++p) {
            int idx = p * 256 + t;
            int row = idx >> 4, f4 = idx & 15;
            int grow = m0 + row; if (grow > N_NODES - 1) grow = N_NODES - 1;
            const float4 v = *reinterpret_cast<const float4*>(X + (size_t)grow * N_FEAT + kt + f4 * 4);
            ushort4 h; h.x = f2bf(v.x); h.y = f2bf(v.y); h.z = f2bf(v.z); h.w = f2bf(v.w);
            int g = f4 >> 1;
            int off = row * 64 + (((g ^ (row & 7)) << 3)) + ((f4 & 1) << 2);
            *reinterpret_cast<ushort4*>(&sA[off]) = h;
        }
        // stage B (W1 rows n0..n0+127)
        #pragma unroll
        for (int p = 0; p < 8; ++p) {
            int idx = p * 256 + t;
            int row = idx >> 4, f4 = idx & 15;
            const float4 v = *reinterpret_cast<const float4*>(W1 + (size_t)(n0 + row) * N_FEAT + kt + f4 * 4);
            ushort4 h; h.x = f2bf(v.x); h.y = f2bf(v.y); h.z = f2bf(v.z); h.w = f2bf(v.w);
            int g = f4 >> 1;
            int off = row * 64 + (((g ^ (row & 7)) << 3)) + ((f4 & 1) << 2);
            *reinterpret_cast<ushort4*>(&sB[off]) = h;
        }
        __syncthreads();
        #pragma unroll
        for (int kk = 0; kk < 2; ++kk) {
            const int g = kk * 4 + hi;
            s16x8 a[4], b[4];
            #pragma unroll
            for (int i = 0; i < 4; ++i) {
                int row = wr * 64 + i * 16 + lo;
                a[i] = *reinterpret_cast<const s16x8*>(&sA[row * 64 + ((g ^ (row & 7)) << 3)]);
            }
            #pragma unroll
            for (int j = 0; j < 4; ++j) {
                int row = wc * 64 + j * 16 + lo;
                b[j] = *reinterpret_cast<const s16x8*>(&sB[row * 64 + ((g ^ (row & 7)) << 3)]);
            }
            #pragma unroll
            for (int i = 0; i < 4; ++i)
                #pragma unroll
                for (int j = 0; j < 4; ++j)
                    acc[i][j] = __builtin_amdgcn_mfma_f32_16x16x32_bf16(a[i], b[j], acc[i][j], 0, 0, 0);
        }
        __syncthreads();
    }
    // epilogue: relu + bf16 store
    #pragma unroll
    for (int i = 0; i < 4; ++i) {
        int rbase = m0 + wr * 64 + i * 16 + hi * 4;
        #pragma unroll
        for (int j = 0; j < 4; ++j) {
            int col = n0 + wc * 64 + j * 16 + lo;
            #pragma unroll
            for (int r = 0; r < 4; ++r) {
                int row = rbase + r;
                if (row < N_NODES) {
                    float v = acc[i][j][r];
                    H[(size_t)row * N_HID + col] = f2bf(fmaxf(v, 0.0f));
                }
            }
        }
    }
}

// ---------------- GEMM2: out0 = H @ W2^T (fp32 out), 128x64 tile ---------------
__launch_bounds__(256)
__global__ void gemm2_k(const ushort* __restrict__ H, const float* __restrict__ W2,
                        float* __restrict__ out) {
    __shared__ ushort sA[128 * 64];
    __shared__ ushort sB[64 * 64];
    const int m0 = blockIdx.x * 128;
    const int t = threadIdx.x;
    const int wid = t >> 6, lane = t & 63;
    const int lo = lane & 15, hi = lane >> 4;

    f32x4 acc[2][4] = {};

    for (int kt = 0; kt < N_HID; kt += 64) {
        // stage A: H tile 128x64 bf16, direct 16B copies
        #pragma unroll
        for (int p = 0; p < 4; ++p) {
            int idx = p * 256 + t;
            int row = idx >> 3, g = idx & 7;
            int grow = m0 + row; if (grow > N_NODES - 1) grow = N_NODES - 1;
            uint4 v = *reinterpret_cast<const uint4*>(H + (size_t)grow * N_HID + kt + g * 8);
            *reinterpret_cast<uint4*>(&sA[row * 64 + ((g ^ (row & 7)) << 3)]) = v;
        }
        // stage B: W2 64 rows x 64 k (fp32 -> bf16)
        #pragma unroll
        for (int p = 0; p < 4; ++p) {
            int idx = p * 256 + t;
            int row = idx >> 4, f4 = idx & 15;
            const float4 v = *reinterpret_cast<const float4*>(W2 + (size_t)row * N_HID + kt + f4 * 4);
            ushort4 h; h.x = f2bf(v.x); h.y = f2bf(v.y); h.z = f2bf(v.z); h.w = f2bf(v.w);
            int g = f4 >> 1;
            int off = row * 64 + ((g ^ (row & 7)) << 3) + ((f4 & 1) << 2);
            *reinterpret_cast<ushort4*>(&sB[off]) = h;
        }
        __syncthreads();
        #pragma unroll
        for (int kk = 0; kk < 2; ++kk) {
            const int g = kk * 4 + hi;
            s16x8 a[2], b[4];
            #pragma unroll
            for (int i = 0; i < 2; ++i) {
                int row = wid * 32 + i * 16 + lo;
                a[i] = *reinterpret_cast<const s16x8*>(&sA[row * 64 + ((g ^ (row & 7)) << 3)]);
            }
            #pragma unroll
            for (int j = 0; j < 4; ++j) {
                int row = j * 16 + lo;
                b[j] = *reinterpret_cast<const s16x8*>(&sB[row * 64 + ((g ^ (row & 7)) << 3)]);
            }
            #pragma unroll
            for (int i = 0; i < 2; ++i)
                #pragma unroll
                for (int j = 0; j < 4; ++j)
                    acc[i][j] = __builtin_amdgcn_mfma_f32_16x16x32_bf16(a[i], b[j], acc[i][j], 0, 0, 0);
        }
        __syncthreads();
    }
    #pragma unroll
    for (int i = 0; i < 2; ++i) {
        int rbase = m0 + wid * 32 + i * 16 + hi * 4;
        #pragma unroll
        for (int j = 0; j < 4; ++j) {
            int col = j * 16 + lo;
            #pragma unroll
            for (int r = 0; r < 4; ++r) {
                int row = rbase + r;
                if (row < N_NODES) out[(size_t)row * N_CLS + col] = acc[i][j][r];
            }
        }
    }
}

// ---------------- degree / dinv ------------------------------------------------
__global__ void deg_k(const int* __restrict__ dst, int* __restrict__ deg) {
    int e = blockIdx.x * 256 + threadIdx.x;
    if (e < N_EDGES) atomicAdd(&deg[dst[e]], 1);
}

__global__ void dinv_k(const int* __restrict__ deg, float* __restrict__ dinv) {
    int n = blockIdx.x * 256 + threadIdx.x;
    if (n < N_NODES) dinv[n] = rsqrtf((float)deg[n] + 1.0f);  // +1 self loop
}

// ---------------- CSR build: scan + scatter ------------------------------------
__device__ __forceinline__ int wave_incl_scan(int v, int lane) {
    #pragma unroll
    for (int d = 1; d < 64; d <<= 1) {
        int u = __shfl_up(v, d, 64);
        if (lane >= d) v += u;
    }
    return v;
}

__global__ void scan_p1(const int* __restrict__ cnt, int* __restrict__ partial) {
    int i = blockIdx.x * 256 + threadIdx.x;
    int v = (i < N_NODES) ? cnt[i] : 0;
    #pragma unroll
    for (int d = 32; d; d >>= 1) v += __shfl_xor(v, d, 64);
    __shared__ int wt[4];
    int wid = threadIdx.x >> 6, lane = threadIdx.x & 63;
    if (lane == 0) wt[wid] = v;
    __syncthreads();
    if (threadIdx.x == 0) partial[blockIdx.x] = wt[0] + wt[1] + wt[2] + wt[3];
}

__global__ void scan_p2(const int* __restrict__ partial, int* __restrict__ chunkoff,
                        int* __restrict__ row_ptr) {
    int t = threadIdx.x;
    int v = (t < 196) ? partial[t] : 0;
    int lane = t & 63, wid = t >> 6;
    int incl = wave_incl_scan(v, lane);
    __shared__ int wt[4];
    if (lane == 63) wt[wid] = incl;
    __syncthreads();
    int woff = 0;
    for (int w = 0; w < wid; ++w) woff += wt[w];
    int excl = incl - v + woff;
    if (t < 196) chunkoff[t] = excl;
    if (t == 0) row_ptr[N_NODES] = N_EDGES;
}

__global__ void scan_p3(const int* __restrict__ cnt, const int* __restrict__ chunkoff,
                        int* __restrict__ row_ptr) {
    int i = blockIdx.x * 256 + threadIdx.x;
    int v = (i < N_NODES) ? cnt[i] : 0;
    int lane = threadIdx.x & 63, wid = threadIdx.x >> 6;
    int incl = wave_incl_scan(v, lane);
    __shared__ int wt[4];
    if (lane == 63) wt[wid] = incl;
    __syncthreads();
    int woff = 0;
    for (int w = 0; w < wid; ++w) woff += wt[w];
    int excl = incl - v + woff;
    if (i < N_NODES) row_ptr[i] = chunkoff[blockIdx.x] + excl;
}

__global__ void scatter_k(const int* __restrict__ src, const int* __restrict__ dst,
                          const float* __restrict__ dinv, const int* __restrict__ row_ptr,
                          int* __restrict__ cursor, int2* __restrict__ csr) {
    int e = blockIdx.x * 256 + threadIdx.x;
    if (e >= N_EDGES) return;
    int s = src[e], d = dst[e];
    int pos = atomicAdd(&cursor[d], 1);
    csr[row_ptr[d] + pos] = make_int2(s, __float_as_int(dinv[s] * dinv[d]));
}

// ---------------- one APPNP hop: class-chunked, XCD-affine ---------------------
// 4 chunks of 16 classes. Per chunk the gather slice of `prev` is 50000*64B =
// 3.2MB < 4MB per-XCD L2. Chunk c is pinned to XCDs {2c,2c+1} via the
// blockIdx%8 round-robin, and the mapping is stable across hops, so the slice
// an XCD writes this hop is the one it gathers from next hop (L2-resident).
// Wave = 16 edge-slots x 4 lanes (f32x4 each = 64B row-chunk), 32 edges/iter.
// csr and h0 are streamed nontemporal so they don't evict the resident slice.
__launch_bounds__(256)
__global__ void hop_k(const float* __restrict__ prev, const float* __restrict__ h0,
                      float* __restrict__ next, const int2* __restrict__ csr,
                      const int* __restrict__ row_ptr, const float* __restrict__ dinv) {
    const int bid = blockIdx.x;
    const int wid = threadIdx.x >> 6;
    const int lane = threadIdx.x & 63;
    const int xs = bid & 7;                 // XCD slot (blockIdx % 8 round-robin)
    const int chunk = xs >> 1;              // class chunk 0..3 -> XCD pair
    const int node = ((((bid >> 3) << 1) | (xs & 1)) << 2) + wid;  // covers [0,50000) per chunk
    const int slot = lane >> 2;             // edge slot 0..15
    const int cl = lane & 3;                // 16B sub-chunk within 64B row-chunk
    const int cb = chunk * 16 + cl * 4;     // class offset of this lane's f32x4

    const int beg = row_ptr[node], end = row_ptr[node + 1];

    f32x4 acc = {0.f, 0.f, 0.f, 0.f};

    for (int ib = beg; ib < end; ib += 32) {
        const int i0 = ib + slot, i1 = i0 + 16;
        const long long v0 = __builtin_nontemporal_load(
            reinterpret_cast<const long long*>(csr + (i0 < end ? i0 : beg)));
        const long long v1 = __builtin_nontemporal_load(
            reinterpret_cast<const long long*>(csr + (i1 < end ? i1 : beg)));
        const int s0 = (int)(v0 & 0xffffffffll);
        const int s1 = (int)(v1 & 0xffffffffll);
        const float w0 = (i0 < end) ? __int_as_float((int)(v0 >> 32)) : 0.0f;
        const float w1 = (i1 < end) ? __int_as_float((int)(v1 >> 32)) : 0.0f;
        const f32x4 p0 = *reinterpret_cast<const f32x4*>(prev + (size_t)s0 * N_CLS + cb);
        const f32x4 p1 = *reinterpret_cast<const f32x4*>(prev + (size_t)s1 * N_CLS + cb);
        #pragma unroll
        for (int c = 0; c < 4; ++c) {
            acc[c] = fmaf(w0, p0[c], acc[c]);
            acc[c] = fmaf(w1, p1[c], acc[c]);
        }
    }

    // fold the 16 edge slots (lane bits 2..5)
    #pragma unroll
    for (int c = 0; c < 4; ++c) {
        acc[c] += __shfl_xor(acc[c], 4, 64);
        acc[c] += __shfl_xor(acc[c], 8, 64);
        acc[c] += __shfl_xor(acc[c], 16, 64);
        acc[c] += __shfl_xor(acc[c], 32, 64);
    }

    if (slot == 0) {
        const float di = dinv[node];
        const float wself = di * di;
        const size_t off = (size_t)node * N_CLS + cb;
        const f32x4 pv = *reinterpret_cast<const f32x4*>(prev + off);  // L2-resident slice
        const f32x4 hh = __builtin_nontemporal_load(
            reinterpret_cast<const f32x4*>(h0 + off));
        f32x4 r;
        #pragma unroll
        for (int c = 0; c < 4; ++c)
            r[c] = 0.9f * fmaf(wself, pv[c], acc[c]) + 0.1f * hh[c];
        *reinterpret_cast<f32x4*>(next + off) = r;
    }
}

// ---------------- log_softmax over 64 classes, wave per row --------------------
__launch_bounds__(256)
__global__ void logsm_k(const float* __restrict__ in, float* __restrict__ out) {
    int r = (blockIdx.x * 256 + threadIdx.x) >> 6;
    int lane = threadIdx.x & 63;
    if (r >= N_NODES) return;
    float v = in[(size_t)r * N_CLS + lane];
    float m = v;
    #pragma unroll
    for (int d = 32; d; d >>= 1) m = fmaxf(m, __shfl_xor(m, d, 64));
    float e = __expf(v - m);
    float s = e;
    #pragma unroll
    for (int d = 32; d; d >>= 1) s += __shfl_xor(s, d, 64);
    out[(size_t)r * N_CLS + lane] = (v - m) - __logf(s);
}

extern "C" void kernel_launch(void* const* d_in, const int* in_sizes, int n_in,
                              void* d_out, int out_size, void* d_ws, size_t ws_size,
                              hipStream_t stream) {
    const float* X  = (const float*)d_in[0];
    const int*   EI = (const int*)d_in[1];
    const float* W1 = (const float*)d_in[2];
    const float* W2 = (const float*)d_in[3];
    const int* src = EI;
    const int* dst = EI + N_EDGES;

    char* ws = (char*)d_ws;
    ushort* H      = (ushort*)(ws + 0);            // 25,600,000 B
    float*  h0     = (float*)(ws + 25600000);      // 12,800,000 B
    float*  pp0    = (float*)(ws + 38400000);      // 12,800,000 B
    float*  pp1    = (float*)(ws + 51200000);      // 12,800,000 B
    int2*   csr    = (int2*)(ws + 64000000);       // 12,800,000 B
    int*    deg    = (int*)(ws + 76800000);        // 200,704 B
    float*  dinv   = (float*)(ws + 77000704);      // 200,704 B
    int*    rptr   = (int*)(ws + 77201408);        // 200,704 B
    int*    cursor = (int*)(ws + 77402112);        // 200,704 B
    int*    part   = (int*)(ws + 77602816);        // 1,024 B
    int*    coff   = (int*)(ws + 77603840);        // 1,024 B

    hipMemsetAsync(deg, 0, N_NODES * sizeof(int), stream);
    hipMemsetAsync(cursor, 0, N_NODES * sizeof(int), stream);

    gemm1_k<<<dim3(391, 2), 256, 0, stream>>>(X, W1, H);
    gemm2_k<<<391, 256, 0, stream>>>(H, W2, h0);

    deg_k<<<6250, 256, 0, stream>>>(dst, deg);
    dinv_k<<<196, 256, 0, stream>>>(deg, dinv);
    scan_p1<<<196, 256, 0, stream>>>(deg, part);
    scan_p2<<<1, 256, 0, stream>>>(part, coff, rptr);
    scan_p3<<<196, 256, 0, stream>>>(deg, coff, rptr);
    scatter_k<<<6250, 256, 0, stream>>>(src, dst, dinv, rptr, cursor, csr);

    const float* p = h0;
    float* bufs[2] = {pp0, pp1};
    for (int k = 0; k < K_HOPS; ++k) {
        float* nx = bufs[k & 1];
        // 50000 blocks: 4 class-chunks x 12500 blocks, chunk = (blockIdx%8)>>1
        hop_k<<<50000, 256, 0, stream>>>(p, h0, nx, csr, rptr, dinv);
        p = nx;
    }
    logsm_k<<<12500, 256, 0, stream>>>(p, (float*)d_out);
}

// Round 3
// 1173.936 us; speedup vs baseline: 1.0704x; 1.0704x over previous
//
#include <hip/hip_runtime.h>
#include <hip/hip_bf16.h>
#include <cstdint>
#include <cstddef>

#define N_NODES 50000
#define N_EDGES 1600000
#define N_FEAT  512
#define N_HID   256
#define N_CLS   64
#define K_HOPS  10
#define CH_STRIDE ((size_t)N_NODES * 16)   // floats per class-chunk plane

typedef __attribute__((ext_vector_type(4))) float f32x4;
typedef __attribute__((ext_vector_type(8))) short s16x8;

__device__ __forceinline__ ushort f2bf(float f) {
    uint32_t u = __float_as_uint(f);
    uint32_t r = (u + 0x7FFFu + ((u >> 16) & 1u)) >> 16;
    return (ushort)r;
}

// ---------------- GEMM1: H = relu(X @ W1^T), bf16 MFMA, 128x128 tile, BK=64 ----
__launch_bounds__(256)
__global__ void gemm1_k(const float* __restrict__ X, const float* __restrict__ W1,
                        ushort* __restrict__ H) {
    __shared__ ushort sA[128 * 64];
    __shared__ ushort sB[128 * 64];
    const int m0 = blockIdx.x * 128;
    const int n0 = blockIdx.y * 128;
    const int t = threadIdx.x;
    const int wid = t >> 6, lane = t & 63;
    const int wr = wid >> 1, wc = wid & 1;
    const int lo = lane & 15, hi = lane >> 4;

    f32x4 acc[4][4] = {};

    for (int kt = 0; kt < N_FEAT; kt += 64) {
        // stage A (fp32 -> bf16), 128 rows x 64 k
        #pragma unroll
        for (int p = 0; p < 8; ++p) {
            int idx = p * 256 + t;
            int row = idx >> 4, f4 = idx & 15;
            int grow = m0 + row; if (grow > N_NODES - 1) grow = N_NODES - 1;
            const float4 v = *reinterpret_cast<const float4*>(X + (size_t)grow * N_FEAT + kt + f4 * 4);
            ushort4 h; h.x = f2bf(v.x); h.y = f2bf(v.y); h.z = f2bf(v.z); h.w = f2bf(v.w);
            int g = f4 >> 1;
            int off = row * 64 + (((g ^ (row & 7)) << 3)) + ((f4 & 1) << 2);
            *reinterpret_cast<ushort4*>(&sA[off]) = h;
        }
        // stage B (W1 rows n0..n0+127)
        #pragma unroll
        for (int p = 0; p < 8; ++p) {
            int idx = p * 256 + t;
            int row = idx >> 4, f4 = idx & 15;
            const float4 v = *reinterpret_cast<const float4*>(W1 + (size_t)(n0 + row) * N_FEAT + kt + f4 * 4);
            ushort4 h; h.x = f2bf(v.x); h.y = f2bf(v.y); h.z = f2bf(v.z); h.w = f2bf(v.w);
            int g = f4 >> 1;
            int off = row * 64 + (((g ^ (row & 7)) << 3)) + ((f4 & 1) << 2);
            *reinterpret_cast<ushort4*>(&sB[off]) = h;
        }
        __syncthreads();
        #pragma unroll
        for (int kk = 0; kk < 2; ++kk) {
            const int g = kk * 4 + hi;
            s16x8 a[4], b[4];
            #pragma unroll
            for (int i = 0; i < 4; ++i) {
                int row = wr * 64 + i * 16 + lo;
                a[i] = *reinterpret_cast<const s16x8*>(&sA[row * 64 + ((g ^ (row & 7)) << 3)]);
            }
            #pragma unroll
            for (int j = 0; j < 4; ++j) {
                int row = wc * 64 + j * 16 + lo;
                b[j] = *reinterpret_cast<const s16x8*>(&sB[row * 64 + ((g ^ (row & 7)) << 3)]);
            }
            #pragma unroll
            for (int i = 0; i < 4; ++i)
                #pragma unroll
                for (int j = 0; j < 4; ++j)
                    acc[i][j] = __builtin_amdgcn_mfma_f32_16x16x32_bf16(a[i], b[j], acc[i][j], 0, 0, 0);
        }
        __syncthreads();
    }
    // epilogue: relu + bf16 store
    #pragma unroll
    for (int i = 0; i < 4; ++i) {
        int rbase = m0 + wr * 64 + i * 16 + hi * 4;
        #pragma unroll
        for (int j = 0; j < 4; ++j) {
            int col = n0 + wc * 64 + j * 16 + lo;
            #pragma unroll
            for (int r = 0; r < 4; ++r) {
                int row = rbase + r;
                if (row < N_NODES) {
                    float v = acc[i][j][r];
                    H[(size_t)row * N_HID + col] = f2bf(fmaxf(v, 0.0f));
                }
            }
        }
    }
}

// ------- GEMM2: out0 = H @ W2^T, 128x64 tile, CHUNK-MAJOR output [4][N][16] ----
__launch_bounds__(256)
__global__ void gemm2_k(const ushort* __restrict__ H, const float* __restrict__ W2,
                        float* __restrict__ out) {
    __shared__ ushort sA[128 * 64];
    __shared__ ushort sB[64 * 64];
    const int m0 = blockIdx.x * 128;
    const int t = threadIdx.x;
    const int wid = t >> 6, lane = t & 63;
    const int lo = lane & 15, hi = lane >> 4;

    f32x4 acc[2][4] = {};

    for (int kt = 0; kt < N_HID; kt += 64) {
        // stage A: H tile 128x64 bf16, direct 16B copies
        #pragma unroll
        for (int p = 0; p < 4; ++p) {
            int idx = p * 256 + t;
            int row = idx >> 3, g = idx & 7;
            int grow = m0 + row; if (grow > N_NODES - 1) grow = N_NODES - 1;
            uint4 v = *reinterpret_cast<const uint4*>(H + (size_t)grow * N_HID + kt + g * 8);
            *reinterpret_cast<uint4*>(&sA[row * 64 + ((g ^ (row & 7)) << 3)]) = v;
        }
        // stage B: W2 64 rows x 64 k (fp32 -> bf16)
        #pragma unroll
        for (int p = 0; p < 4; ++p) {
            int idx = p * 256 + t;
            int row = idx >> 4, f4 = idx & 15;
            const float4 v = *reinterpret_cast<const float4*>(W2 + (size_t)row * N_HID + kt + f4 * 4);
            ushort4 h; h.x = f2bf(v.x); h.y = f2bf(v.y); h.z = f2bf(v.z); h.w = f2bf(v.w);
            int g = f4 >> 1;
            int off = row * 64 + ((g ^ (row & 7)) << 3) + ((f4 & 1) << 2);
            *reinterpret_cast<ushort4*>(&sB[off]) = h;
        }
        __syncthreads();
        #pragma unroll
        for (int kk = 0; kk < 2; ++kk) {
            const int g = kk * 4 + hi;
            s16x8 a[2], b[4];
            #pragma unroll
            for (int i = 0; i < 2; ++i) {
                int row = wid * 32 + i * 16 + lo;
                a[i] = *reinterpret_cast<const s16x8*>(&sA[row * 64 + ((g ^ (row & 7)) << 3)]);
            }
            #pragma unroll
            for (int j = 0; j < 4; ++j) {
                int row = j * 16 + lo;
                b[j] = *reinterpret_cast<const s16x8*>(&sB[row * 64 + ((g ^ (row & 7)) << 3)]);
            }
            #pragma unroll
            for (int i = 0; i < 2; ++i)
                #pragma unroll
                for (int j = 0; j < 4; ++j)
                    acc[i][j] = __builtin_amdgcn_mfma_f32_16x16x32_bf16(a[i], b[j], acc[i][j], 0, 0, 0);
        }
        __syncthreads();
    }
    // chunk-major store: class col = j*16+lo -> plane j, within lo
    #pragma unroll
    for (int i = 0; i < 2; ++i) {
        int rbase = m0 + wid * 32 + i * 16 + hi * 4;
        #pragma unroll
        for (int j = 0; j < 4; ++j) {
            #pragma unroll
            for (int r = 0; r < 4; ++r) {
                int row = rbase + r;
                if (row < N_NODES)
                    out[(size_t)j * CH_STRIDE + (size_t)row * 16 + lo] = acc[i][j][r];
            }
        }
    }
}

// ---------------- degree / dinv ------------------------------------------------
__global__ void deg_k(const int* __restrict__ dst, int* __restrict__ deg) {
    int e = blockIdx.x * 256 + threadIdx.x;
    if (e < N_EDGES) atomicAdd(&deg[dst[e]], 1);
}

__global__ void dinv_k(const int* __restrict__ deg, float* __restrict__ dinv) {
    int n = blockIdx.x * 256 + threadIdx.x;
    if (n < N_NODES) dinv[n] = rsqrtf((float)deg[n] + 1.0f);  // +1 self loop
}

// ---------------- CSR build: scan + scatter ------------------------------------
__device__ __forceinline__ int wave_incl_scan(int v, int lane) {
    #pragma unroll
    for (int d = 1; d < 64; d <<= 1) {
        int u = __shfl_up(v, d, 64);
        if (lane >= d) v += u;
    }
    return v;
}

__global__ void scan_p1(const int* __restrict__ cnt, int* __restrict__ partial) {
    int i = blockIdx.x * 256 + threadIdx.x;
    int v = (i < N_NODES) ? cnt[i] : 0;
    #pragma unroll
    for (int d = 32; d; d >>= 1) v += __shfl_xor(v, d, 64);
    __shared__ int wt[4];
    int wid = threadIdx.x >> 6, lane = threadIdx.x & 63;
    if (lane == 0) wt[wid] = v;
    __syncthreads();
    if (threadIdx.x == 0) partial[blockIdx.x] = wt[0] + wt[1] + wt[2] + wt[3];
}

__global__ void scan_p2(const int* __restrict__ partial, int* __restrict__ chunkoff,
                        int* __restrict__ row_ptr) {
    int t = threadIdx.x;
    int v = (t < 196) ? partial[t] : 0;
    int lane = t & 63, wid = t >> 6;
    int incl = wave_incl_scan(v, lane);
    __shared__ int wt[4];
    if (lane == 63) wt[wid] = incl;
    __syncthreads();
    int woff = 0;
    for (int w = 0; w < wid; ++w) woff += wt[w];
    int excl = incl - v + woff;
    if (t < 196) chunkoff[t] = excl;
    if (t == 0) row_ptr[N_NODES] = N_EDGES;
}

__global__ void scan_p3(const int* __restrict__ cnt, const int* __restrict__ chunkoff,
                        int* __restrict__ row_ptr) {
    int i = blockIdx.x * 256 + threadIdx.x;
    int v = (i < N_NODES) ? cnt[i] : 0;
    int lane = threadIdx.x & 63, wid = threadIdx.x >> 6;
    int incl = wave_incl_scan(v, lane);
    __shared__ int wt[4];
    if (lane == 63) wt[wid] = incl;
    __syncthreads();
    int woff = 0;
    for (int w = 0; w < wid; ++w) woff += wt[w];
    int excl = incl - v + woff;
    if (i < N_NODES) row_ptr[i] = chunkoff[blockIdx.x] + excl;
}

__global__ void scatter_k(const int* __restrict__ src, const int* __restrict__ dst,
                          const float* __restrict__ dinv, const int* __restrict__ row_ptr,
                          int* __restrict__ cursor, int2* __restrict__ csr) {
    int e = blockIdx.x * 256 + threadIdx.x;
    if (e >= N_EDGES) return;
    int s = src[e], d = dst[e];
    int pos = atomicAdd(&cursor[d], 1);
    csr[row_ptr[d] + pos] = make_int2(s, __float_as_int(dinv[s] * dinv[d]));
}

// ---------------- one APPNP hop: class-chunked, chunk-major, XCD-affine --------
// prev/h0/next are chunk-major [4][N_NODES][16]. Per chunk the gather slice is
// 50000*64B = 3.2MB CONTIGUOUS (< 4MB per-XCD L2, full line utilization).
// Chunk c pinned to XCDs {2c,2c+1} via blockIdx%8 round-robin -> each XCD only
// gathers from its own 3.2MB plane; after within-hop warm-up gathers hit L2.
// csr/h0 loads and the `next` store are nontemporal so streams don't evict the
// resident plane. Wave = 16 edge-slots x 4 lanes (f32x4 = 64B row), 32 edges/it.
__launch_bounds__(256)
__global__ void hop_k(const float* __restrict__ prev, const float* __restrict__ h0,
                      float* __restrict__ next, const int2* __restrict__ csr,
                      const int* __restrict__ row_ptr, const float* __restrict__ dinv) {
    const int bid = blockIdx.x;
    const int wid = threadIdx.x >> 6;
    const int lane = threadIdx.x & 63;
    const int xs = bid & 7;                 // XCD slot (blockIdx % 8 round-robin)
    const int chunk = xs >> 1;              // class chunk 0..3 -> XCD pair
    const int node = ((((bid >> 3) << 1) | (xs & 1)) << 2) + wid;  // [0,50000) per chunk
    const int slot = lane >> 2;             // edge slot 0..15
    const int cl4 = (lane & 3) << 2;        // float offset within 16-float row

    const float* __restrict__ pc = prev + (size_t)chunk * CH_STRIDE;
    const float* __restrict__ hc = h0   + (size_t)chunk * CH_STRIDE;
    float* __restrict__ nc       = next + (size_t)chunk * CH_STRIDE;

    const int beg = row_ptr[node], end = row_ptr[node + 1];

    f32x4 acc = {0.f, 0.f, 0.f, 0.f};

    for (int ib = beg; ib < end; ib += 32) {
        const int i0 = ib + slot, i1 = i0 + 16;
        const long long v0 = __builtin_nontemporal_load(
            reinterpret_cast<const long long*>(csr + (i0 < end ? i0 : beg)));
        const long long v1 = __builtin_nontemporal_load(
            reinterpret_cast<const long long*>(csr + (i1 < end ? i1 : beg)));
        const int s0 = (int)(v0 & 0xffffffffll);
        const int s1 = (int)(v1 & 0xffffffffll);
        const float w0 = (i0 < end) ? __int_as_float((int)(v0 >> 32)) : 0.0f;
        const float w1 = (i1 < end) ? __int_as_float((int)(v1 >> 32)) : 0.0f;
        const f32x4 p0 = *reinterpret_cast<const f32x4*>(pc + (size_t)s0 * 16 + cl4);
        const f32x4 p1 = *reinterpret_cast<const f32x4*>(pc + (size_t)s1 * 16 + cl4);
        #pragma unroll
        for (int c = 0; c < 4; ++c) {
            acc[c] = fmaf(w0, p0[c], acc[c]);
            acc[c] = fmaf(w1, p1[c], acc[c]);
        }
    }

    // fold the 16 edge slots (lane bits 2..5)
    #pragma unroll
    for (int c = 0; c < 4; ++c) {
        acc[c] += __shfl_xor(acc[c], 4, 64);
        acc[c] += __shfl_xor(acc[c], 8, 64);
        acc[c] += __shfl_xor(acc[c], 16, 64);
        acc[c] += __shfl_xor(acc[c], 32, 64);
    }

    if (slot == 0) {
        const float di = dinv[node];
        const float wself = di * di;
        const size_t off = (size_t)node * 16 + cl4;
        const f32x4 pv = *reinterpret_cast<const f32x4*>(pc + off);   // L2-resident
        const f32x4 hh = __builtin_nontemporal_load(
            reinterpret_cast<const f32x4*>(hc + off));
        f32x4 r;
        #pragma unroll
        for (int c = 0; c < 4; ++c)
            r[c] = 0.9f * fmaf(wself, pv[c], acc[c]) + 0.1f * hh[c];
        __builtin_nontemporal_store(r, reinterpret_cast<f32x4*>(nc + off));
    }
}

// -------- log_softmax over 64 classes, chunk-major in, row-major out -----------
__launch_bounds__(256)
__global__ void logsm_k(const float* __restrict__ in, float* __restrict__ out) {
    int r = (blockIdx.x * 256 + threadIdx.x) >> 6;
    int lane = threadIdx.x & 63;
    if (r >= N_NODES) return;
    float v = in[(size_t)(lane >> 4) * CH_STRIDE + (size_t)r * 16 + (lane & 15)];
    float m = v;
    #pragma unroll
    for (int d = 32; d; d >>= 1) m = fmaxf(m, __shfl_xor(m, d, 64));
    float e = __expf(v - m);
    float s = e;
    #pragma unroll
    for (int d = 32; d; d >>= 1) s += __shfl_xor(s, d, 64);
    out[(size_t)r * N_CLS + lane] = (v - m) - __logf(s);
}

extern "C" void kernel_launch(void* const* d_in, const int* in_sizes, int n_in,
                              void* d_out, int out_size, void* d_ws, size_t ws_size,
                              hipStream_t stream) {
    const float* X  = (const float*)d_in[0];
    const int*   EI = (const int*)d_in[1];
    const float* W1 = (const float*)d_in[2];
    const float* W2 = (const float*)d_in[3];
    const int* src = EI;
    const int* dst = EI + N_EDGES;

    char* ws = (char*)d_ws;
    ushort* H      = (ushort*)(ws + 0);            // 25,600,000 B
    float*  h0     = (float*)(ws + 25600000);      // 12,800,000 B (chunk-major)
    float*  pp0    = (float*)(ws + 38400000);      // 12,800,000 B (chunk-major)
    float*  pp1    = (float*)(ws + 51200000);      // 12,800,000 B (chunk-major)
    int2*   csr    = (int2*)(ws + 64000000);       // 12,800,000 B
    int*    deg    = (int*)(ws + 76800000);        // 200,704 B
    float*  dinv   = (float*)(ws + 77000704);      // 200,704 B
    int*    rptr   = (int*)(ws + 77201408);        // 200,704 B
    int*    cursor = (int*)(ws + 77402112);        // 200,704 B
    int*    part   = (int*)(ws + 77602816);        // 1,024 B
    int*    coff   = (int*)(ws + 77603840);        // 1,024 B

    hipMemsetAsync(deg, 0, N_NODES * sizeof(int), stream);
    hipMemsetAsync(cursor, 0, N_NODES * sizeof(int), stream);

    gemm1_k<<<dim3(391, 2), 256, 0, stream>>>(X, W1, H);
    gemm2_k<<<391, 256, 0, stream>>>(H, W2, h0);

    deg_k<<<6250, 256, 0, stream>>>(dst, deg);
    dinv_k<<<196, 256, 0, stream>>>(deg, dinv);
    scan_p1<<<196, 256, 0, stream>>>(deg, part);
    scan_p2<<<1, 256, 0, stream>>>(part, coff, rptr);
    scan_p3<<<196, 256, 0, stream>>>(deg, coff, rptr);
    scatter_k<<<6250, 256, 0, stream>>>(src, dst, dinv, rptr, cursor, csr);

    const float* p = h0;
    float* bufs[2] = {pp0, pp1};
    for (int k = 0; k < K_HOPS; ++k) {
        float* nx = bufs[k & 1];
        // 50000 blocks: 4 class-chunks x 12500, chunk = (blockIdx%8)>>1
        hop_k<<<50000, 256, 0, stream>>>(p, h0, nx, csr, rptr, dinv);
        p = nx;
    }
    logsm_k<<<12500, 256, 0, stream>>>(p, (float*)d_out);
}

// Round 4
// 929.988 us; speedup vs baseline: 1.3512x; 1.2623x over previous
//
#include <hip/hip_runtime.h>
#include <hip/hip_bf16.h>
#include <cstdint>
#include <cstddef>

#define N_NODES 50000
#define N_EDGES 1600000
#define N_FEAT  512
#define N_HID   256
#define N_CLS   64
#define K_HOPS  10
#define CH_STRIDE ((size_t)N_NODES * 16)   // floats per class-chunk plane
#define P16(d) (((d) + 15) & ~15)
#define STAGE_CAP 256                       // csr entries staged in LDS per wave
#define HOP_GRID 12504                      // 8 | grid; covers 3126 cb per chunk

typedef __attribute__((ext_vector_type(4))) float f32x4;
typedef __attribute__((ext_vector_type(8))) short s16x8;

__device__ __forceinline__ ushort f2bf(float f) {
    uint32_t u = __float_as_uint(f);
    uint32_t r = (u + 0x7FFFu + ((u >> 16) & 1u)) >> 16;
    return (ushort)r;
}

// ---------------- GEMM1: H = relu(X @ W1^T), bf16 MFMA, 128x128 tile, BK=64 ----
__launch_bounds__(256)
__global__ void gemm1_k(const float* __restrict__ X, const float* __restrict__ W1,
                        ushort* __restrict__ H) {
    __shared__ ushort sA[128 * 64];
    __shared__ ushort sB[128 * 64];
    const int m0 = blockIdx.x * 128;
    const int n0 = blockIdx.y * 128;
    const int t = threadIdx.x;
    const int wid = t >> 6, lane = t & 63;
    const int wr = wid >> 1, wc = wid & 1;
    const int lo = lane & 15, hi = lane >> 4;

    f32x4 acc[4][4] = {};

    for (int kt = 0; kt < N_FEAT; kt += 64) {
        #pragma unroll
        for (int p = 0; p < 8; ++p) {
            int idx = p * 256 + t;
            int row = idx >> 4, f4 = idx & 15;
            int grow = m0 + row; if (grow > N_NODES - 1) grow = N_NODES - 1;
            const float4 v = *reinterpret_cast<const float4*>(X + (size_t)grow * N_FEAT + kt + f4 * 4);
            ushort4 h; h.x = f2bf(v.x); h.y = f2bf(v.y); h.z = f2bf(v.z); h.w = f2bf(v.w);
            int g = f4 >> 1;
            int off = row * 64 + (((g ^ (row & 7)) << 3)) + ((f4 & 1) << 2);
            *reinterpret_cast<ushort4*>(&sA[off]) = h;
        }
        #pragma unroll
        for (int p = 0; p < 8; ++p) {
            int idx = p * 256 + t;
            int row = idx >> 4, f4 = idx & 15;
            const float4 v = *reinterpret_cast<const float4*>(W1 + (size_t)(n0 + row) * N_FEAT + kt + f4 * 4);
            ushort4 h; h.x = f2bf(v.x); h.y = f2bf(v.y); h.z = f2bf(v.z); h.w = f2bf(v.w);
            int g = f4 >> 1;
            int off = row * 64 + (((g ^ (row & 7)) << 3)) + ((f4 & 1) << 2);
            *reinterpret_cast<ushort4*>(&sB[off]) = h;
        }
        __syncthreads();
        #pragma unroll
        for (int kk = 0; kk < 2; ++kk) {
            const int g = kk * 4 + hi;
            s16x8 a[4], b[4];
            #pragma unroll
            for (int i = 0; i < 4; ++i) {
                int row = wr * 64 + i * 16 + lo;
                a[i] = *reinterpret_cast<const s16x8*>(&sA[row * 64 + ((g ^ (row & 7)) << 3)]);
            }
            #pragma unroll
            for (int j = 0; j < 4; ++j) {
                int row = wc * 64 + j * 16 + lo;
                b[j] = *reinterpret_cast<const s16x8*>(&sB[row * 64 + ((g ^ (row & 7)) << 3)]);
            }
            #pragma unroll
            for (int i = 0; i < 4; ++i)
                #pragma unroll
                for (int j = 0; j < 4; ++j)
                    acc[i][j] = __builtin_amdgcn_mfma_f32_16x16x32_bf16(a[i], b[j], acc[i][j], 0, 0, 0);
        }
        __syncthreads();
    }
    #pragma unroll
    for (int i = 0; i < 4; ++i) {
        int rbase = m0 + wr * 64 + i * 16 + hi * 4;
        #pragma unroll
        for (int j = 0; j < 4; ++j) {
            int col = n0 + wc * 64 + j * 16 + lo;
            #pragma unroll
            for (int r = 0; r < 4; ++r) {
                int row = rbase + r;
                if (row < N_NODES) {
                    float v = acc[i][j][r];
                    H[(size_t)row * N_HID + col] = f2bf(fmaxf(v, 0.0f));
                }
            }
        }
    }
}

// ------- GEMM2: out0 = H @ W2^T, 128x64 tile, CHUNK-MAJOR output [4][N][16] ----
__launch_bounds__(256)
__global__ void gemm2_k(const ushort* __restrict__ H, const float* __restrict__ W2,
                        float* __restrict__ out) {
    __shared__ ushort sA[128 * 64];
    __shared__ ushort sB[64 * 64];
    const int m0 = blockIdx.x * 128;
    const int t = threadIdx.x;
    const int wid = t >> 6, lane = t & 63;
    const int lo = lane & 15, hi = lane >> 4;

    f32x4 acc[2][4] = {};

    for (int kt = 0; kt < N_HID; kt += 64) {
        #pragma unroll
        for (int p = 0; p < 4; ++p) {
            int idx = p * 256 + t;
            int row = idx >> 3, g = idx & 7;
            int grow = m0 + row; if (grow > N_NODES - 1) grow = N_NODES - 1;
            uint4 v = *reinterpret_cast<const uint4*>(H + (size_t)grow * N_HID + kt + g * 8);
            *reinterpret_cast<uint4*>(&sA[row * 64 + ((g ^ (row & 7)) << 3)]) = v;
        }
        #pragma unroll
        for (int p = 0; p < 4; ++p) {
            int idx = p * 256 + t;
            int row = idx >> 4, f4 = idx & 15;
            const float4 v = *reinterpret_cast<const float4*>(W2 + (size_t)row * N_HID + kt + f4 * 4);
            ushort4 h; h.x = f2bf(v.x); h.y = f2bf(v.y); h.z = f2bf(v.z); h.w = f2bf(v.w);
            int g = f4 >> 1;
            int off = row * 64 + ((g ^ (row & 7)) << 3) + ((f4 & 1) << 2);
            *reinterpret_cast<ushort4*>(&sB[off]) = h;
        }
        __syncthreads();
        #pragma unroll
        for (int kk = 0; kk < 2; ++kk) {
            const int g = kk * 4 + hi;
            s16x8 a[2], b[4];
            #pragma unroll
            for (int i = 0; i < 2; ++i) {
                int row = wid * 32 + i * 16 + lo;
                a[i] = *reinterpret_cast<const s16x8*>(&sA[row * 64 + ((g ^ (row & 7)) << 3)]);
            }
            #pragma unroll
            for (int j = 0; j < 4; ++j) {
                int row = j * 16 + lo;
                b[j] = *reinterpret_cast<const s16x8*>(&sB[row * 64 + ((g ^ (row & 7)) << 3)]);
            }
            #pragma unroll
            for (int i = 0; i < 2; ++i)
                #pragma unroll
                for (int j = 0; j < 4; ++j)
                    acc[i][j] = __builtin_amdgcn_mfma_f32_16x16x32_bf16(a[i], b[j], acc[i][j], 0, 0, 0);
        }
        __syncthreads();
    }
    // chunk-major store: class col = j*16+lo -> plane j, within lo
    #pragma unroll
    for (int i = 0; i < 2; ++i) {
        int rbase = m0 + wid * 32 + i * 16 + hi * 4;
        #pragma unroll
        for (int j = 0; j < 4; ++j) {
            #pragma unroll
            for (int r = 0; r < 4; ++r) {
                int row = rbase + r;
                if (row < N_NODES)
                    out[(size_t)j * CH_STRIDE + (size_t)row * 16 + lo] = acc[i][j][r];
            }
        }
    }
}

// ---------------- degree / dinv ------------------------------------------------
__global__ void deg_k(const int* __restrict__ dst, int* __restrict__ deg) {
    int e = blockIdx.x * 256 + threadIdx.x;
    if (e < N_EDGES) atomicAdd(&deg[dst[e]], 1);
}

__global__ void dinv_k(const int* __restrict__ deg, float* __restrict__ dinv) {
    int n = blockIdx.x * 256 + threadIdx.x;
    if (n < N_NODES) dinv[n] = rsqrtf((float)deg[n] + 1.0f);  // +1 self loop
}

// ------------- CSR build: scan over PADDED degrees + scatter + padfill ---------
__device__ __forceinline__ int wave_incl_scan(int v, int lane) {
    #pragma unroll
    for (int d = 1; d < 64; d <<= 1) {
        int u = __shfl_up(v, d, 64);
        if (lane >= d) v += u;
    }
    return v;
}

__global__ void scan_p1(const int* __restrict__ cnt, int* __restrict__ partial) {
    int i = blockIdx.x * 256 + threadIdx.x;
    int v = (i < N_NODES) ? P16(cnt[i]) : 0;
    #pragma unroll
    for (int d = 32; d; d >>= 1) v += __shfl_xor(v, d, 64);
    __shared__ int wt[4];
    int wid = threadIdx.x >> 6, lane = threadIdx.x & 63;
    if (lane == 0) wt[wid] = v;
    __syncthreads();
    if (threadIdx.x == 0) partial[blockIdx.x] = wt[0] + wt[1] + wt[2] + wt[3];
}

__global__ void scan_p2(const int* __restrict__ partial, int* __restrict__ chunkoff,
                        int* __restrict__ row_ptr) {
    int t = threadIdx.x;
    int v = (t < 196) ? partial[t] : 0;
    int lane = t & 63, wid = t >> 6;
    int incl = wave_incl_scan(v, lane);
    __shared__ int wt[4];
    if (lane == 63) wt[wid] = incl;
    __syncthreads();
    int woff = 0;
    for (int w = 0; w < wid; ++w) woff += wt[w];
    int excl = incl - v + woff;
    if (t < 196) chunkoff[t] = excl;
    if (t == 0) row_ptr[N_NODES] = wt[0] + wt[1] + wt[2] + wt[3];  // padded total
}

__global__ void scan_p3(const int* __restrict__ cnt, const int* __restrict__ chunkoff,
                        int* __restrict__ row_ptr) {
    int i = blockIdx.x * 256 + threadIdx.x;
    int v = (i < N_NODES) ? P16(cnt[i]) : 0;
    int lane = threadIdx.x & 63, wid = threadIdx.x >> 6;
    int incl = wave_incl_scan(v, lane);
    __shared__ int wt[4];
    if (lane == 63) wt[wid] = incl;
    __syncthreads();
    int woff = 0;
    for (int w = 0; w < wid; ++w) woff += wt[w];
    int excl = incl - v + woff;
    if (i < N_NODES) row_ptr[i] = chunkoff[blockIdx.x] + excl;
}

__global__ void scatter_k(const int* __restrict__ src, const int* __restrict__ dst,
                          const float* __restrict__ dinv, const int* __restrict__ row_ptr,
                          int* __restrict__ cursor, int2* __restrict__ csr) {
    int e = blockIdx.x * 256 + threadIdx.x;
    if (e >= N_EDGES) return;
    int s = src[e], d = dst[e];
    int pos = atomicAdd(&cursor[d], 1);
    csr[row_ptr[d] + pos] = make_int2(s, __float_as_int(dinv[s] * dinv[d]));
}

// fill pad slots [deg, P16(deg)) with zero-weight edges to node 0
__global__ void padfill_k(const int* __restrict__ deg, const int* __restrict__ row_ptr,
                          int2* __restrict__ csr) {
    int n = blockIdx.x * 256 + threadIdx.x;
    if (n >= N_NODES) return;
    int d = deg[n];
    int base = row_ptr[n] + d;
    int pad = P16(d) - d;
    for (int i = 0; i < pad; ++i) csr[base + i] = make_int2(0, 0);
}

// ---------------- one APPNP hop: chunk-major planes, LDS-staged CSR ------------
// Geometry: HOP_GRID blocks x 4 waves. chunk = (bid%8)>>1 (XCD-pair affinity,
// planes proven L2-resident in r3: FETCH == csr only). Each wave owns 4
// consecutive nodes; their padded csr segments form ONE contiguous range,
// staged into LDS up-front with 4 independent nt loads (HBM latency paid once,
// in parallel) so the inner loop's only global dependency is the L2 gather.
// Wave = 16 slots x 4 lanes; 16-edge batches; segments are 16-multiples so each
// batch belongs to exactly one node (no predication, uniform scalar branches).
__launch_bounds__(256)
__global__ void hop_k(const float* __restrict__ prev, const float* __restrict__ h0,
                      float* __restrict__ next, const int2* __restrict__ csr,
                      const int* __restrict__ row_ptr, const float* __restrict__ dinv) {
    __shared__ int2 scsr[4][STAGE_CAP];
    const int bid = blockIdx.x;
    const int wid = threadIdx.x >> 6;
    const int lane = threadIdx.x & 63;
    const int xs = bid & 7;
    const int chunk = xs >> 1;
    const int cb = ((bid >> 3) << 1) | (xs & 1);   // within-chunk block id
    const int nb = cb * 16 + wid * 4;              // first of this wave's 4 nodes
    if (nb >= N_NODES) return;
    const int slot = lane >> 2;                    // edge slot 0..15
    const int cl4 = (lane & 3) << 2;               // float offset in 16-f row

    const float* __restrict__ pc = prev + (size_t)chunk * CH_STRIDE;
    const float* __restrict__ hc = h0   + (size_t)chunk * CH_STRIDE;
    float*       __restrict__ nc = next + (size_t)chunk * CH_STRIDE;

    // padded segment boundaries -> SGPRs (uniform loop bounds)
    const int b0 = __builtin_amdgcn_readfirstlane(row_ptr[nb]);
    const int e0 = __builtin_amdgcn_readfirstlane(row_ptr[nb + 1]);
    const int e1 = __builtin_amdgcn_readfirstlane(row_ptr[nb + 2]);
    const int e2 = __builtin_amdgcn_readfirstlane(row_ptr[nb + 3]);
    const int e3 = __builtin_amdgcn_readfirstlane(row_ptr[nb + 4]);
    const int tot = e3 - b0;

    // stage combined range into LDS (4 independent nt loads per lane)
    int2* sw = scsr[wid];
    #pragma unroll
    for (int k = 0; k < 4; ++k) {
        int off = k * 64 + lane;
        if (off < tot && off < STAGE_CAP) {
            long long v = __builtin_nontemporal_load(
                reinterpret_cast<const long long*>(csr + b0 + off));
            sw[off] = make_int2((int)(v & 0xffffffffll), (int)(v >> 32));
        }
    }

    f32x4 a0 = {0.f,0.f,0.f,0.f}, a1 = a0, a2 = a0, a3 = a0;

#define NODE_LOOP(Bg, Eg, ACC)                                                   \
    for (int ib = (Bg); ib < (Eg); ib += 16) {                                   \
        int2 e;                                                                  \
        if (ib - b0 < STAGE_CAP) {                                               \
            e = sw[ib - b0 + slot];                                              \
        } else {                                                                 \
            long long v = __builtin_nontemporal_load(                            \
                reinterpret_cast<const long long*>(csr + ib + slot));            \
            e = make_int2((int)(v & 0xffffffffll), (int)(v >> 32));              \
        }                                                                        \
        const float w = __int_as_float(e.y);                                     \
        const f32x4 p = *reinterpret_cast<const f32x4*>(                         \
            pc + (size_t)e.x * 16 + cl4);                                        \
        ACC[0] = fmaf(w, p[0], ACC[0]);                                          \
        ACC[1] = fmaf(w, p[1], ACC[1]);                                          \
        ACC[2] = fmaf(w, p[2], ACC[2]);                                          \
        ACC[3] = fmaf(w, p[3], ACC[3]);                                          \
    }

    NODE_LOOP(b0, e0, a0)
    NODE_LOOP(e0, e1, a1)
    NODE_LOOP(e1, e2, a2)
    NODE_LOOP(e2, e3, a3)
#undef NODE_LOOP

    // fold 16 slots (lane bits 2..5) for each node's accumulator
    #pragma unroll
    for (int c = 0; c < 4; ++c) {
        a0[c] += __shfl_xor(a0[c], 4, 64);  a0[c] += __shfl_xor(a0[c], 8, 64);
        a0[c] += __shfl_xor(a0[c], 16, 64); a0[c] += __shfl_xor(a0[c], 32, 64);
        a1[c] += __shfl_xor(a1[c], 4, 64);  a1[c] += __shfl_xor(a1[c], 8, 64);
        a1[c] += __shfl_xor(a1[c], 16, 64); a1[c] += __shfl_xor(a1[c], 32, 64);
        a2[c] += __shfl_xor(a2[c], 4, 64);  a2[c] += __shfl_xor(a2[c], 8, 64);
        a2[c] += __shfl_xor(a2[c], 16, 64); a2[c] += __shfl_xor(a2[c], 32, 64);
        a3[c] += __shfl_xor(a3[c], 4, 64);  a3[c] += __shfl_xor(a3[c], 8, 64);
        a3[c] += __shfl_xor(a3[c], 16, 64); a3[c] += __shfl_xor(a3[c], 32, 64);
    }

    // slots 0..3 each own one node: one coalesced 256B load/store set per wave
    if (slot < 4) {
        const int node = nb + slot;
        const float di = dinv[node];
        const float wself = di * di;
        f32x4 av = a0;
        if (slot == 1) av = a1;
        if (slot == 2) av = a2;
        if (slot == 3) av = a3;
        const size_t off = (size_t)node * 16 + cl4;
        const f32x4 pv = *reinterpret_cast<const f32x4*>(pc + off);  // L2-resident
        const f32x4 hh = __builtin_nontemporal_load(
            reinterpret_cast<const f32x4*>(hc + off));
        f32x4 r;
        #pragma unroll
        for (int c = 0; c < 4; ++c)
            r[c] = 0.9f * fmaf(wself, pv[c], av[c]) + 0.1f * hh[c];
        __builtin_nontemporal_store(r, reinterpret_cast<f32x4*>(nc + off));
    }
}

// -------- log_softmax over 64 classes, chunk-major in, row-major out -----------
__launch_bounds__(256)
__global__ void logsm_k(const float* __restrict__ in, float* __restrict__ out) {
    int r = (blockIdx.x * 256 + threadIdx.x) >> 6;
    int lane = threadIdx.x & 63;
    if (r >= N_NODES) return;
    float v = in[(size_t)(lane >> 4) * CH_STRIDE + (size_t)r * 16 + (lane & 15)];
    float m = v;
    #pragma unroll
    for (int d = 32; d; d >>= 1) m = fmaxf(m, __shfl_xor(m, d, 64));
    float e = __expf(v - m);
    float s = e;
    #pragma unroll
    for (int d = 32; d; d >>= 1) s += __shfl_xor(s, d, 64);
    out[(size_t)r * N_CLS + lane] = (v - m) - __logf(s);
}

extern "C" void kernel_launch(void* const* d_in, const int* in_sizes, int n_in,
                              void* d_out, int out_size, void* d_ws, size_t ws_size,
                              hipStream_t stream) {
    const float* X  = (const float*)d_in[0];
    const int*   EI = (const int*)d_in[1];
    const float* W1 = (const float*)d_in[2];
    const float* W2 = (const float*)d_in[3];
    const int* src = EI;
    const int* dst = EI + N_EDGES;

    char* ws = (char*)d_ws;
    // H occupies [0, 25.6MB) during the GEMMs; the padded CSR (<= 3.2M entries
    // = 25.6MB) reuses the same region afterwards (stream-ordered: scatter_k
    // runs strictly after gemm2_k consumed H).
    ushort* H      = (ushort*)(ws + 0);            // 25,600,000 B
    int2*   csr    = (int2*)(ws + 0);              // reuse (padded csr <= 18.8 MB)
    float*  h0     = (float*)(ws + 25600000);      // 12,800,000 B (chunk-major)
    float*  pp0    = (float*)(ws + 38400000);      // 12,800,000 B (chunk-major)
    float*  pp1    = (float*)(ws + 51200000);      // 12,800,000 B (chunk-major)
    int*    deg    = (int*)(ws + 64000000);        // 200,000 B
    float*  dinv   = (float*)(ws + 64256000);      // 200,000 B
    int*    rptr   = (int*)(ws + 64512000);        // 200,004 B
    int*    cursor = (int*)(ws + 64768000);        // 200,000 B
    int*    part   = (int*)(ws + 65024000);        // 784 B
    int*    coff   = (int*)(ws + 65028096);        // 784 B

    hipMemsetAsync(deg, 0, N_NODES * sizeof(int), stream);
    hipMemsetAsync(cursor, 0, N_NODES * sizeof(int), stream);

    gemm1_k<<<dim3(391, 2), 256, 0, stream>>>(X, W1, H);
    gemm2_k<<<391, 256, 0, stream>>>(H, W2, h0);

    deg_k<<<6250, 256, 0, stream>>>(dst, deg);
    dinv_k<<<196, 256, 0, stream>>>(deg, dinv);
    scan_p1<<<196, 256, 0, stream>>>(deg, part);
    scan_p2<<<1, 256, 0, stream>>>(part, coff, rptr);
    scan_p3<<<196, 256, 0, stream>>>(deg, coff, rptr);
    scatter_k<<<6250, 256, 0, stream>>>(src, dst, dinv, rptr, cursor, csr);
    padfill_k<<<196, 256, 0, stream>>>(deg, rptr, csr);

    const float* p = h0;
    float* bufs[2] = {pp0, pp1};
    for (int k = 0; k < K_HOPS; ++k) {
        float* nx = bufs[k & 1];
        hop_k<<<HOP_GRID, 256, 0, stream>>>(p, h0, nx, csr, rptr, dinv);
        p = nx;
    }
    logsm_k<<<12500, 256, 0, stream>>>(p, (float*)d_out);
}

// Round 5
// 899.072 us; speedup vs baseline: 1.3977x; 1.0344x over previous
//
#include <hip/hip_runtime.h>
#include <hip/hip_bf16.h>
#include <cstdint>
#include <cstddef>

#define N_NODES 50000
#define N_EDGES 1600000
#define N_FEAT  512
#define N_HID   256
#define N_CLS   64
#define K_HOPS  10
#define NPAD    50016                       // plane rows incl. dummy zero row
#define DUMMY   N_NODES                     // pad edges point here (zeroed)
#define CH_STRIDE ((size_t)NPAD * 16)       // floats per class-chunk plane
#define P16(d) (((d) + 15) & ~15)
#define STAGE_CAP 256                       // csr entries staged in LDS per wave
#define HOP_GRID 12504                      // 8 | grid; covers 3126 cb per chunk
#define NPS 6250                            // nodes per XCD slice

typedef __attribute__((ext_vector_type(4))) float f32x4;
typedef __attribute__((ext_vector_type(8))) short s16x8;

__device__ __forceinline__ ushort f2bf(float f) {
    uint32_t u = __float_as_uint(f);
    uint32_t r = (u + 0x7FFFu + ((u >> 16) & 1u)) >> 16;
    return (ushort)r;
}

// ---------------- GEMM1: H = relu(X @ W1^T), bf16 MFMA, 128x128 tile, BK=64 ----
__launch_bounds__(256)
__global__ void gemm1_k(const float* __restrict__ X, const float* __restrict__ W1,
                        ushort* __restrict__ H) {
    __shared__ ushort sA[128 * 64];
    __shared__ ushort sB[128 * 64];
    const int m0 = blockIdx.x * 128;
    const int n0 = blockIdx.y * 128;
    const int t = threadIdx.x;
    const int wid = t >> 6, lane = t & 63;
    const int wr = wid >> 1, wc = wid & 1;
    const int lo = lane & 15, hi = lane >> 4;

    f32x4 acc[4][4] = {};

    for (int kt = 0; kt < N_FEAT; kt += 64) {
        #pragma unroll
        for (int p = 0; p < 8; ++p) {
            int idx = p * 256 + t;
            int row = idx >> 4, f4 = idx & 15;
            int grow = m0 + row; if (grow > N_NODES - 1) grow = N_NODES - 1;
            const float4 v = *reinterpret_cast<const float4*>(X + (size_t)grow * N_FEAT + kt + f4 * 4);
            ushort4 h; h.x = f2bf(v.x); h.y = f2bf(v.y); h.z = f2bf(v.z); h.w = f2bf(v.w);
            int g = f4 >> 1;
            int off = row * 64 + (((g ^ (row & 7)) << 3)) + ((f4 & 1) << 2);
            *reinterpret_cast<ushort4*>(&sA[off]) = h;
        }
        #pragma unroll
        for (int p = 0; p < 8; ++p) {
            int idx = p * 256 + t;
            int row = idx >> 4, f4 = idx & 15;
            const float4 v = *reinterpret_cast<const float4*>(W1 + (size_t)(n0 + row) * N_FEAT + kt + f4 * 4);
            ushort4 h; h.x = f2bf(v.x); h.y = f2bf(v.y); h.z = f2bf(v.z); h.w = f2bf(v.w);
            int g = f4 >> 1;
            int off = row * 64 + (((g ^ (row & 7)) << 3)) + ((f4 & 1) << 2);
            *reinterpret_cast<ushort4*>(&sB[off]) = h;
        }
        __syncthreads();
        #pragma unroll
        for (int kk = 0; kk < 2; ++kk) {
            const int g = kk * 4 + hi;
            s16x8 a[4], b[4];
            #pragma unroll
            for (int i = 0; i < 4; ++i) {
                int row = wr * 64 + i * 16 + lo;
                a[i] = *reinterpret_cast<const s16x8*>(&sA[row * 64 + ((g ^ (row & 7)) << 3)]);
            }
            #pragma unroll
            for (int j = 0; j < 4; ++j) {
                int row = wc * 64 + j * 16 + lo;
                b[j] = *reinterpret_cast<const s16x8*>(&sB[row * 64 + ((g ^ (row & 7)) << 3)]);
            }
            #pragma unroll
            for (int i = 0; i < 4; ++i)
                #pragma unroll
                for (int j = 0; j < 4; ++j)
                    acc[i][j] = __builtin_amdgcn_mfma_f32_16x16x32_bf16(a[i], b[j], acc[i][j], 0, 0, 0);
        }
        __syncthreads();
    }
    #pragma unroll
    for (int i = 0; i < 4; ++i) {
        int rbase = m0 + wr * 64 + i * 16 + hi * 4;
        #pragma unroll
        for (int j = 0; j < 4; ++j) {
            int col = n0 + wc * 64 + j * 16 + lo;
            #pragma unroll
            for (int r = 0; r < 4; ++r) {
                int row = rbase + r;
                if (row < N_NODES) {
                    float v = acc[i][j][r];
                    H[(size_t)row * N_HID + col] = f2bf(fmaxf(v, 0.0f));
                }
            }
        }
    }
}

// ---- GEMM2: h~0 = dinv * (H @ W2^T), chunk-major [4][NPAD][16] ---------------
__launch_bounds__(256)
__global__ void gemm2_k(const ushort* __restrict__ H, const float* __restrict__ W2,
                        const float* __restrict__ dinv, float* __restrict__ out) {
    __shared__ ushort sA[128 * 64];
    __shared__ ushort sB[64 * 64];
    const int m0 = blockIdx.x * 128;
    const int t = threadIdx.x;
    const int wid = t >> 6, lane = t & 63;
    const int lo = lane & 15, hi = lane >> 4;

    f32x4 acc[2][4] = {};

    for (int kt = 0; kt < N_HID; kt += 64) {
        #pragma unroll
        for (int p = 0; p < 4; ++p) {
            int idx = p * 256 + t;
            int row = idx >> 3, g = idx & 7;
            int grow = m0 + row; if (grow > N_NODES - 1) grow = N_NODES - 1;
            uint4 v = *reinterpret_cast<const uint4*>(H + (size_t)grow * N_HID + kt + g * 8);
            *reinterpret_cast<uint4*>(&sA[row * 64 + ((g ^ (row & 7)) << 3)]) = v;
        }
        #pragma unroll
        for (int p = 0; p < 4; ++p) {
            int idx = p * 256 + t;
            int row = idx >> 4, f4 = idx & 15;
            const float4 v = *reinterpret_cast<const float4*>(W2 + (size_t)row * N_HID + kt + f4 * 4);
            ushort4 h; h.x = f2bf(v.x); h.y = f2bf(v.y); h.z = f2bf(v.z); h.w = f2bf(v.w);
            int g = f4 >> 1;
            int off = row * 64 + ((g ^ (row & 7)) << 3) + ((f4 & 1) << 2);
            *reinterpret_cast<ushort4*>(&sB[off]) = h;
        }
        __syncthreads();
        #pragma unroll
        for (int kk = 0; kk < 2; ++kk) {
            const int g = kk * 4 + hi;
            s16x8 a[2], b[4];
            #pragma unroll
            for (int i = 0; i < 2; ++i) {
                int row = wid * 32 + i * 16 + lo;
                a[i] = *reinterpret_cast<const s16x8*>(&sA[row * 64 + ((g ^ (row & 7)) << 3)]);
            }
            #pragma unroll
            for (int j = 0; j < 4; ++j) {
                int row = j * 16 + lo;
                b[j] = *reinterpret_cast<const s16x8*>(&sB[row * 64 + ((g ^ (row & 7)) << 3)]);
            }
            #pragma unroll
            for (int i = 0; i < 2; ++i)
                #pragma unroll
                for (int j = 0; j < 4; ++j)
                    acc[i][j] = __builtin_amdgcn_mfma_f32_16x16x32_bf16(a[i], b[j], acc[i][j], 0, 0, 0);
        }
        __syncthreads();
    }
    // chunk-major store, scaled by dinv[row]
    #pragma unroll
    for (int i = 0; i < 2; ++i) {
        int rbase = m0 + wid * 32 + i * 16 + hi * 4;
        #pragma unroll
        for (int r = 0; r < 4; ++r) {
            int row = rbase + r;
            if (row < N_NODES) {
                const float dv = dinv[row];
                #pragma unroll
                for (int j = 0; j < 4; ++j)
                    out[(size_t)j * CH_STRIDE + (size_t)row * 16 + lo] = acc[i][j][r] * dv;
            }
        }
    }
}

// ---------------- degree / dinv / rd (XCD-sliced deg) --------------------------
// grid 6250x8: bid&7 = XCD slot owns dst slice [slot*NPS,(slot+1)*NPS).
// Each slot streams all edges (L3-fed); atomics land in its own L2 slice.
__global__ void deg_k(const int* __restrict__ dst, int* __restrict__ deg) {
    const int slice = blockIdx.x & 7;
    const int e = (blockIdx.x >> 3) * 256 + threadIdx.x;
    const int lo = slice * NPS;
    const int d = dst[e];
    if ((unsigned)(d - lo) < (unsigned)NPS) atomicAdd(&deg[d], 1);
}

__global__ void dinv_k(const int* __restrict__ deg, float* __restrict__ dinv,
                       float* __restrict__ rd) {
    int n = blockIdx.x * 256 + threadIdx.x;
    if (n < N_NODES) {
        float dp1 = (float)deg[n] + 1.0f;     // +1 self loop
        dinv[n] = rsqrtf(dp1);
        rd[n]   = sqrtf(dp1);
    }
}

// ------------- CSR build: scan over PADDED degrees + scatter + padfill ---------
__device__ __forceinline__ int wave_incl_scan(int v, int lane) {
    #pragma unroll
    for (int d = 1; d < 64; d <<= 1) {
        int u = __shfl_up(v, d, 64);
        if (lane >= d) v += u;
    }
    return v;
}

__global__ void scan_p1(const int* __restrict__ cnt, int* __restrict__ partial) {
    int i = blockIdx.x * 256 + threadIdx.x;
    int v = (i < N_NODES) ? P16(cnt[i]) : 0;
    #pragma unroll
    for (int d = 32; d; d >>= 1) v += __shfl_xor(v, d, 64);
    __shared__ int wt[4];
    int wid = threadIdx.x >> 6, lane = threadIdx.x & 63;
    if (lane == 0) wt[wid] = v;
    __syncthreads();
    if (threadIdx.x == 0) partial[blockIdx.x] = wt[0] + wt[1] + wt[2] + wt[3];
}

__global__ void scan_p2(const int* __restrict__ partial, int* __restrict__ chunkoff,
                        int* __restrict__ row_ptr) {
    int t = threadIdx.x;
    int v = (t < 196) ? partial[t] : 0;
    int lane = t & 63, wid = t >> 6;
    int incl = wave_incl_scan(v, lane);
    __shared__ int wt[4];
    if (lane == 63) wt[wid] = incl;
    __syncthreads();
    int woff = 0;
    for (int w = 0; w < wid; ++w) woff += wt[w];
    int excl = incl - v + woff;
    if (t < 196) chunkoff[t] = excl;
    if (t == 0) row_ptr[N_NODES] = wt[0] + wt[1] + wt[2] + wt[3];  // padded total
}

__global__ void scan_p3(const int* __restrict__ cnt, const int* __restrict__ chunkoff,
                        int* __restrict__ row_ptr) {
    int i = blockIdx.x * 256 + threadIdx.x;
    int v = (i < N_NODES) ? P16(cnt[i]) : 0;
    int lane = threadIdx.x & 63, wid = threadIdx.x >> 6;
    int incl = wave_incl_scan(v, lane);
    __shared__ int wt[4];
    if (lane == 63) wt[wid] = incl;
    __syncthreads();
    int woff = 0;
    for (int w = 0; w < wid; ++w) woff += wt[w];
    int excl = incl - v + woff;
    if (i < N_NODES) row_ptr[i] = chunkoff[blockIdx.x] + excl;
}

// XCD-sliced scatter: csr entry = 4B src index only. All atomics + writes for a
// slice come from one XCD -> L2-local cursor lines, full-line csr writebacks.
__global__ void scatter_k(const int* __restrict__ src, const int* __restrict__ dst,
                          const int* __restrict__ row_ptr,
                          int* __restrict__ cursor, int* __restrict__ csr) {
    const int slice = blockIdx.x & 7;
    const int e = (blockIdx.x >> 3) * 256 + threadIdx.x;
    const int lo = slice * NPS;
    const int d = dst[e];
    if ((unsigned)(d - lo) < (unsigned)NPS) {
        int pos = atomicAdd(&cursor[d], 1);
        csr[row_ptr[d] + pos] = src[e];
    }
}

// fill pad slots [deg, P16(deg)) with DUMMY (zeroed plane row)
__global__ void padfill_k(const int* __restrict__ deg, const int* __restrict__ row_ptr,
                          int* __restrict__ csr) {
    int n = blockIdx.x * 256 + threadIdx.x;
    if (n >= N_NODES) return;
    int d = deg[n];
    int base = row_ptr[n] + d;
    int pad = P16(d) - d;
    for (int i = 0; i < pad; ++i) csr[base + i] = DUMMY;
}

// zero the dummy row (node DUMMY) in all 4 chunk planes of the 3 state buffers
__global__ void zdum_k(float* __restrict__ b0, float* __restrict__ b1,
                       float* __restrict__ b2) {
    int t = threadIdx.x;
    if (t >= 192) return;
    float* b = (t < 64) ? b0 : (t < 128) ? b1 : b2;
    int w = t & 63;
    b[(size_t)(w >> 4) * CH_STRIDE + (size_t)DUMMY * 16 + (w & 15)] = 0.0f;
}

// ---------------- one APPNP hop: weightless scaled planes ----------------------
// p~' [d] = 0.9*dinv[d]^2*(sum_{s in N(d)} p~[s] + p~[d]) + 0.1*h~0[d]
// Planes chunk-major [4][NPAD][16], chunk pinned to XCD pair (L2-resident,
// proven r3/r4). csr = 4B src indices, padded to 16-multiples with DUMMY
// (zero row -> adds 0.0, same-line L1 hit). Wave = 16 slots x 4 lanes, 4 nodes
// per wave, combined segment LDS-staged with 4 parallel nt loads.
__launch_bounds__(256)
__global__ void hop_k(const float* __restrict__ prev, const float* __restrict__ h0,
                      float* __restrict__ next, const int* __restrict__ csr,
                      const int* __restrict__ row_ptr, const float* __restrict__ dinv) {
    __shared__ int scsr[4][STAGE_CAP];
    const int bid = blockIdx.x;
    const int wid = threadIdx.x >> 6;
    const int lane = threadIdx.x & 63;
    const int xs = bid & 7;
    const int chunk = xs >> 1;
    const int cb = ((bid >> 3) << 1) | (xs & 1);   // within-chunk block id
    const int nb = cb * 16 + wid * 4;              // first of this wave's 4 nodes
    if (nb >= N_NODES) return;
    const int slot = lane >> 2;                    // edge slot 0..15
    const int cl4 = (lane & 3) << 2;               // float offset in 16-f row

    const float* __restrict__ pc = prev + (size_t)chunk * CH_STRIDE;
    const float* __restrict__ hc = h0   + (size_t)chunk * CH_STRIDE;
    float*       __restrict__ nc = next + (size_t)chunk * CH_STRIDE;

    // padded segment boundaries -> SGPRs (uniform loop bounds)
    const int b0 = __builtin_amdgcn_readfirstlane(row_ptr[nb]);
    const int e0 = __builtin_amdgcn_readfirstlane(row_ptr[nb + 1]);
    const int e1 = __builtin_amdgcn_readfirstlane(row_ptr[nb + 2]);
    const int e2 = __builtin_amdgcn_readfirstlane(row_ptr[nb + 3]);
    const int e3 = __builtin_amdgcn_readfirstlane(row_ptr[nb + 4]);
    const int tot = e3 - b0;

    // stage combined range into LDS (4 independent nt loads per lane)
    int* sw = scsr[wid];
    #pragma unroll
    for (int k = 0; k < 4; ++k) {
        int off = k * 64 + lane;
        if (off < tot && off < STAGE_CAP)
            sw[off] = __builtin_nontemporal_load(csr + b0 + off);
    }

    f32x4 a0 = {0.f,0.f,0.f,0.f}, a1 = a0, a2 = a0, a3 = a0;

#define NODE_LOOP(Bg, Eg, ACC)                                                   \
    for (int ib = (Bg); ib < (Eg); ib += 16) {                                   \
        int s;                                                                   \
        if (ib - b0 < STAGE_CAP) s = sw[ib - b0 + slot];                         \
        else s = __builtin_nontemporal_load(csr + ib + slot);                    \
        const f32x4 p = *reinterpret_cast<const f32x4*>(                         \
            pc + (size_t)s * 16 + cl4);                                          \
        ACC[0] += p[0]; ACC[1] += p[1]; ACC[2] += p[2]; ACC[3] += p[3];          \
    }

    NODE_LOOP(b0, e0, a0)
    NODE_LOOP(e0, e1, a1)
    NODE_LOOP(e1, e2, a2)
    NODE_LOOP(e2, e3, a3)
#undef NODE_LOOP

    // fold 16 slots (lane bits 2..5) for each node's accumulator
    #pragma unroll
    for (int c = 0; c < 4; ++c) {
        a0[c] += __shfl_xor(a0[c], 4, 64);  a0[c] += __shfl_xor(a0[c], 8, 64);
        a0[c] += __shfl_xor(a0[c], 16, 64); a0[c] += __shfl_xor(a0[c], 32, 64);
        a1[c] += __shfl_xor(a1[c], 4, 64);  a1[c] += __shfl_xor(a1[c], 8, 64);
        a1[c] += __shfl_xor(a1[c], 16, 64); a1[c] += __shfl_xor(a1[c], 32, 64);
        a2[c] += __shfl_xor(a2[c], 4, 64);  a2[c] += __shfl_xor(a2[c], 8, 64);
        a2[c] += __shfl_xor(a2[c], 16, 64); a2[c] += __shfl_xor(a2[c], 32, 64);
        a3[c] += __shfl_xor(a3[c], 4, 64);  a3[c] += __shfl_xor(a3[c], 8, 64);
        a3[c] += __shfl_xor(a3[c], 16, 64); a3[c] += __shfl_xor(a3[c], 32, 64);
    }

    // slots 0..3 each own one node: coalesced 256B load/store set per wave
    if (slot < 4) {
        const int node = nb + slot;
        const float di = dinv[node];
        const float di2 = di * di;
        f32x4 av = a0;
        if (slot == 1) av = a1;
        if (slot == 2) av = a2;
        if (slot == 3) av = a3;
        const size_t off = (size_t)node * 16 + cl4;
        const f32x4 pv = *reinterpret_cast<const f32x4*>(pc + off);  // L2-resident
        const f32x4 hh = __builtin_nontemporal_load(
            reinterpret_cast<const f32x4*>(hc + off));
        f32x4 r;
        #pragma unroll
        for (int c = 0; c < 4; ++c)
            r[c] = 0.9f * di2 * (av[c] + pv[c]) + 0.1f * hh[c];
        __builtin_nontemporal_store(r, reinterpret_cast<f32x4*>(nc + off));
    }
}

// ---- log_softmax over 64 classes; input scaled planes, rescale by rd ----------
__launch_bounds__(256)
__global__ void logsm_k(const float* __restrict__ in, const float* __restrict__ rd,
                        float* __restrict__ out) {
    int r = (blockIdx.x * 256 + threadIdx.x) >> 6;
    int lane = threadIdx.x & 63;
    if (r >= N_NODES) return;
    float v = in[(size_t)(lane >> 4) * CH_STRIDE + (size_t)r * 16 + (lane & 15)] * rd[r];
    float m = v;
    #pragma unroll
    for (int d = 32; d; d >>= 1) m = fmaxf(m, __shfl_xor(m, d, 64));
    float e = __expf(v - m);
    float s = e;
    #pragma unroll
    for (int d = 32; d; d >>= 1) s += __shfl_xor(s, d, 64);
    out[(size_t)r * N_CLS + lane] = (v - m) - __logf(s);
}

extern "C" void kernel_launch(void* const* d_in, const int* in_sizes, int n_in,
                              void* d_out, int out_size, void* d_ws, size_t ws_size,
                              hipStream_t stream) {
    const float* X  = (const float*)d_in[0];
    const int*   EI = (const int*)d_in[1];
    const float* W1 = (const float*)d_in[2];
    const float* W2 = (const float*)d_in[3];
    const int* src = EI;
    const int* dst = EI + N_EDGES;

    char* ws = (char*)d_ws;
    const size_t BUF = 4 * CH_STRIDE * sizeof(float);   // 12,804,096 B
    ushort* H      = (ushort*)(ws + 0);                 // 25,600,000 B
    float*  h0t    = (float*)(ws + 25600000);           // BUF (h~0, chunk-major)
    float*  pp0    = (float*)(ws + 25600000 + BUF);     // BUF
    float*  pp1    = (float*)(ws + 25600000 + 2*BUF);   // BUF
    int*    csr    = (int*)  (ws + 64012288);           // <= 9,600,000 B (padded, 4B)
    int*    deg    = (int*)  (ws + 73612288);           // 200,000 B
    float*  dinv   = (float*)(ws + 73812288);           // 200,000 B
    float*  rd     = (float*)(ws + 74012288);           // 200,000 B
    int*    rptr   = (int*)  (ws + 74212288);           // 200,004 B
    int*    cursor = (int*)  (ws + 74412292);           // 200,000 B
    int*    part   = (int*)  (ws + 74612292);           // 784 B
    int*    coff   = (int*)  (ws + 74613076);           // 784 B

    hipMemsetAsync(deg, 0, N_NODES * sizeof(int), stream);
    hipMemsetAsync(cursor, 0, N_NODES * sizeof(int), stream);

    deg_k<<<50000, 256, 0, stream>>>(dst, deg);
    dinv_k<<<196, 256, 0, stream>>>(deg, dinv, rd);
    scan_p1<<<196, 256, 0, stream>>>(deg, part);
    scan_p2<<<1, 256, 0, stream>>>(part, coff, rptr);
    scan_p3<<<196, 256, 0, stream>>>(deg, coff, rptr);
    scatter_k<<<50000, 256, 0, stream>>>(src, dst, rptr, cursor, csr);
    padfill_k<<<196, 256, 0, stream>>>(deg, rptr, csr);
    zdum_k<<<1, 256, 0, stream>>>(h0t, pp0, pp1);

    gemm1_k<<<dim3(391, 2), 256, 0, stream>>>(X, W1, H);
    gemm2_k<<<391, 256, 0, stream>>>(H, W2, dinv, h0t);

    const float* p = h0t;
    float* bufs[2] = {pp0, pp1};
    for (int k = 0; k < K_HOPS; ++k) {
        float* nx = bufs[k & 1];
        hop_k<<<HOP_GRID, 256, 0, stream>>>(p, h0t, nx, csr, rptr, dinv);
        p = nx;
    }
    logsm_k<<<12500, 256, 0, stream>>>(p, rd, (float*)d_out);
}